// Round 7
// baseline (574.615 us; speedup 1.0000x reference)
//
#include <hip/hip_runtime.h>

// PrototypeBank steady-state update, MI355X/gfx950.  Round 11.
//   emb:    [131072, 512] fp32   protos: [1024, 512] fp32
//   out[k]: count>0 ? normalize(0.9*p + 0.1*mean(norm_emb assigned to k)) : p
//
// Round-11: assign is latency-bound (per-wave iter gap ~1900 cyc vs 13.7us
// of total matrix work).  Register pipelining is closed (R7-R9 spill).  New
// mechanism: per-wave LDS ring (5 slots x 2KB) filled by async
// global_load_lds DMA -- zero VGPR cost, no barriers (A-frags are wave-
// private).  Issue-ahead 4, consume under s_waitcnt vmcnt(8); tail issues
// clamped dummy loads so the vmcnt literal stays uniform.  LDS 148KB ->
// 1 block/CU (8 waves); pipeline depth replaces wave-level latency hiding.

#define D 512
#define NPROTO 1024
#define ROWS 64          // embedding rows per workgroup in k1
#define DEPTH 5          // A-ring slots per wave

typedef __attribute__((ext_vector_type(8)))  unsigned short ushort8;
typedef __attribute__((ext_vector_type(8)))  __bf16 bfrag8;
typedef __attribute__((ext_vector_type(16))) float f32x16;

static __device__ inline unsigned short f2bf(float f) {
    unsigned int u = __float_as_uint(f);
    u = u + 0x7FFFu + ((u >> 16) & 1u);   // round-to-nearest-even
    return (unsigned short)(u >> 16);
}

static __device__ __forceinline__ void gload16(const unsigned short* g,
                                               unsigned short* l) {
    __builtin_amdgcn_global_load_lds(
        (const __attribute__((address_space(1))) unsigned int*)g,
        (__attribute__((address_space(3))) unsigned int*)l, 16, 0, 0);
}

// ---------------- k0: normalize prototypes -> packed bf16 A-fragments ----------------
// Packed for 32x32x16 A-operand: group g32 = p>>5 (32 protos), k-step ks (16 cols).
// Consumer lane l reads ((g32*32+ks)*64 + l)*8 shorts.  Also zeroes psum + counts.
__global__ __launch_bounds__(256) void norm_protos_kernel(
    const float* __restrict__ protos, unsigned short* __restrict__ pbf,
    int* __restrict__ counts, float* __restrict__ psum)
{
    const int wave = threadIdx.x >> 6, lane = threadIdx.x & 63;
    const int row = blockIdx.x * 4 + wave;            // grid 256 -> 1024 rows
    const float* src = protos + (size_t)row * D + lane * 8;
    float4 v0 = *(const float4*)src;
    float4 v1 = *(const float4*)(src + 4);
    float ss = v0.x*v0.x + v0.y*v0.y + v0.z*v0.z + v0.w*v0.w
             + v1.x*v1.x + v1.y*v1.y + v1.z*v1.z + v1.w*v1.w;
    #pragma unroll
    for (int off = 32; off > 0; off >>= 1) ss += __shfl_xor(ss, off, 64);
    const float inv = 1.0f / fmaxf(sqrtf(ss), 1e-6f);
    ushort8 w;
    w[0] = f2bf(v0.x*inv); w[1] = f2bf(v0.y*inv); w[2] = f2bf(v0.z*inv); w[3] = f2bf(v0.w*inv);
    w[4] = f2bf(v1.x*inv); w[5] = f2bf(v1.y*inv); w[6] = f2bf(v1.z*inv); w[7] = f2bf(v1.w*inv);
    const size_t dst = (size_t)(row >> 5) * 16384 + (lane >> 1) * 512
                     + (lane & 1) * 256 + (row & 31) * 8;
    *(ushort8*)(pbf + dst) = w;
    const int gid = blockIdx.x * 256 + threadIdx.x;
    const float4 z = make_float4(0.f, 0.f, 0.f, 0.f);
    ((float4*)psum)[gid * 2]     = z;
    ((float4*)psum)[gid * 2 + 1] = z;
    if (blockIdx.x == 0) ((int4*)counts)[threadIdx.x] = (int4){0, 0, 0, 0};
}

// ---------------- k1: argmax over 1024 protos (32x32x16 bf16 MFMA) ----------------
// B: LDS eT 64x512 bf16, XOR-swizzled.  A: per-wave 5-slot LDS ring filled by
// global_load_lds DMA, issue-ahead 4, vmcnt(8) counted waits, no inner barriers.
__global__ __launch_bounds__(512) void assign_kernel(
    const float* __restrict__ emb, const unsigned short* __restrict__ pbf,
    int* __restrict__ assign, float* __restrict__ invnorm, int* __restrict__ counts)
{
    __shared__ __align__(16) unsigned short eT[ROWS * D];            // 64 KB
    __shared__ __align__(16) unsigned short aring[8 * DEPTH * 1024]; // 80 KB
    __shared__ float swmax[8][64];                                   // 2 KB
    __shared__ int   swidx[8][64];                                   // 2 KB
    const int tid = threadIdx.x;
    const int wave = tid >> 6, lane = tid & 63;
    const int rowbase = blockIdx.x * ROWS;
    const int c32 = lane & 31, h = lane >> 5;

    // A-addresses: gA(kk,frag) = pbf + wave*2*16384 + lane*8
    //              + (kk>>5)*262144 + (kk&31)*512 + frag*16384   (shorts)
    const unsigned short* gA = pbf + (size_t)wave * 32768 + lane * 8;
    unsigned short* awu = aring + wave * (DEPTH * 1024);   // wave-uniform ring base

    // prologue: issue ring slots kk=0..3 (8 DMAs) BEFORE staging -> their
    // latency hides under the eT stage + barrier.  Wave-private, no barrier.
    #pragma unroll
    for (int kk = 0; kk < 4; ++kk) {
        const unsigned short* g0 = gA + kk * 512;          // kk<32 -> ng=0
        gload16(g0,         awu + kk * 1024);
        gload16(g0 + 16384, awu + kk * 1024 + 512);
    }

    // --- stage: 8 rows/wave, RAW bf16 (||e|| doesn't change argmax); invnorm saved.
    for (int rr = 0; rr < 8; ++rr) {
        const int rloc = wave * 8 + rr;
        const float* src = emb + (size_t)(rowbase + rloc) * D + lane * 8;
        float4 v0 = *(const float4*)src;
        float4 v1 = *(const float4*)(src + 4);
        float ss = v0.x*v0.x + v0.y*v0.y + v0.z*v0.z + v0.w*v0.w
                 + v1.x*v1.x + v1.y*v1.y + v1.z*v1.z + v1.w*v1.w;
        #pragma unroll
        for (int off = 32; off > 0; off >>= 1) ss += __shfl_xor(ss, off, 64);
        if (lane == 0) invnorm[rowbase + rloc] = 1.0f / fmaxf(sqrtf(ss), 1e-6f);
        ushort8 w;
        w[0] = f2bf(v0.x); w[1] = f2bf(v0.y); w[2] = f2bf(v0.z); w[3] = f2bf(v0.w);
        w[4] = f2bf(v1.x); w[5] = f2bf(v1.y); w[6] = f2bf(v1.z); w[7] = f2bf(v1.w);
        const int slot = lane ^ (rloc & 7);
        *(ushort8*)(&eT[rloc * D + slot * 8]) = w;
    }
    __syncthreads();

    float rv0 = -3.4e38f, rv1 = -3.4e38f;
    int   ri0 = 0,        ri1 = 0;

    const int bbase0 = c32 * D;            // shorts
    const int bbase1 = (32 + c32) * D;
    const int rxor = c32 & 7;

    #pragma unroll
    for (int ng = 0; ng < 2; ++ng) {
        const int pbase = ng * 512 + wave * 64;

        f32x16 acc00 = (f32x16)(0.f), acc01 = (f32x16)(0.f);
        f32x16 acc10 = (f32x16)(0.f), acc11 = (f32x16)(0.f);

        #pragma unroll
        for (int ks = 0; ks < 32; ++ks) {
            const int kk = ng * 32 + ks;
            // issue slot kk+4 (tail: clamp addr to kk=63, L2-hot dummy -> the
            // vmcnt literal stays uniform and slot-kk retirement is guaranteed)
            {
                const int kkn = kk + 4;
                const int kkc = kkn > 63 ? 63 : kkn;
                const unsigned short* g0 = gA + (kkc >> 5) * 262144 + (kkc & 31) * 512;
                unsigned short* ld = awu + (kkn % DEPTH) * 1024;
                gload16(g0,         ld);
                gload16(g0 + 16384, ld + 512);
            }
            // 4 younger slots x 2 loads may remain; slot kk's 2 must retire.
            asm volatile("s_waitcnt vmcnt(8)" ::: "memory");
            const unsigned short* ar = awu + (kk % DEPTH) * 1024;
            const bfrag8 a0 = *(const bfrag8*)(ar + lane * 8);
            const bfrag8 a1 = *(const bfrag8*)(ar + 512 + lane * 8);
            const int slot = ((ks * 2 + h) ^ rxor) * 8;
            const bfrag8 b0 = *(const bfrag8*)(&eT[bbase0 + slot]);
            const bfrag8 b1 = *(const bfrag8*)(&eT[bbase1 + slot]);
            acc00 = __builtin_amdgcn_mfma_f32_32x32x16_bf16(a0, b0, acc00, 0, 0, 0);
            acc01 = __builtin_amdgcn_mfma_f32_32x32x16_bf16(a0, b1, acc01, 0, 0, 0);
            acc10 = __builtin_amdgcn_mfma_f32_32x32x16_bf16(a1, b0, acc10, 0, 0, 0);
            acc11 = __builtin_amdgcn_mfma_f32_32x32x16_bf16(a1, b1, acc11, 0, 0, 0);
        }

        // In-register argmax over protos.  C layout (32x32): col=lane&31,
        // row = (reg&3) + 8*(reg>>2) + 4*(lane>>5).  reg 0..15 then mt 0..1 is
        // strictly ascending proto index -> strict > keeps first max.
        float bv0 = -3.4e38f, bv1 = -3.4e38f;
        int   bi0 = 0,        bi1 = 0;
        #pragma unroll
        for (int j = 0; j < 16; ++j) {
            const int row = (j & 3) + 8 * (j >> 2) + 4 * h;
            const float v0 = acc00[j], v1 = acc01[j];
            if (v0 > bv0) { bv0 = v0; bi0 = pbase + row; }
            if (v1 > bv1) { bv1 = v1; bi1 = pbase + row; }
        }
        #pragma unroll
        for (int j = 0; j < 16; ++j) {
            const int row = 32 + (j & 3) + 8 * (j >> 2) + 4 * h;
            const float v0 = acc10[j], v1 = acc11[j];
            if (v0 > bv0) { bv0 = v0; bi0 = pbase + row; }
            if (v1 > bv1) { bv1 = v1; bi1 = pbase + row; }
        }
        // half-merge (other half owns interleaved rows; tie-break on index)
        {
            const float ov = __shfl_xor(bv0, 32, 64);
            const int   oi = __shfl_xor(bi0, 32, 64);
            if (ov > bv0 || (ov == bv0 && oi < bi0)) { bv0 = ov; bi0 = oi; }
        }
        {
            const float ov = __shfl_xor(bv1, 32, 64);
            const int   oi = __shfl_xor(bi1, 32, 64);
            if (ov > bv1 || (ov == bv1 && oi < bi1)) { bv1 = ov; bi1 = oi; }
        }
        // ng ascending: strictly-greater replaces; ties keep older (smaller idx)
        if (bv0 > rv0) { rv0 = bv0; ri0 = bi0; }
        if (bv1 > rv1) { rv1 = bv1; ri1 = bi1; }
    }

    // drain remaining dummy DMAs before LDS reuse / endpgm
    asm volatile("s_waitcnt vmcnt(0)" ::: "memory");

    if (h == 0) {
        swmax[wave][c32]      = rv0;  swidx[wave][c32]      = ri0;
        swmax[wave][32 + c32] = rv1;  swidx[wave][32 + c32] = ri1;
    }
    __syncthreads();

    if (tid < 64) {
        float v = swmax[0][tid]; int idx = swidx[0][tid];
        #pragma unroll
        for (int w = 1; w < 8; ++w) {
            const float ov = swmax[w][tid];
            const int   oi = swidx[w][tid];
            if (ov > v || (ov == v && oi < idx)) { v = ov; idx = oi; }
        }
        assign[rowbase + tid] = idx;
        atomicAdd(&counts[idx], 1);
    }
}

// ---------------- k2: packed shuffle-scan prefix + segment work-item list ----------------
__global__ __launch_bounds__(1024) void prefix_kernel(
    const int* __restrict__ counts, int* __restrict__ offsets,
    int* __restrict__ cursor, int* __restrict__ items, int* __restrict__ nitems)
{
    __shared__ unsigned wtot[16];
    const int t = threadIdx.x;
    const int lane = t & 63, wv = t >> 6;
    const int c = counts[t];
    const int nseg = (c + 255) >> 8;
    unsigned v = (unsigned)c | ((unsigned)nseg << 20);
    #pragma unroll
    for (int off = 1; off < 64; off <<= 1) {
        const unsigned n = __shfl_up(v, off, 64);
        if (lane >= off) v += n;
    }
    if (lane == 63) wtot[wv] = v;
    __syncthreads();
    if (t < 16) {
        unsigned x = wtot[t];
        #pragma unroll
        for (int off = 1; off < 16; off <<= 1) {
            const unsigned n = __shfl_up(x, off, 16);
            if (t >= off) x += n;
        }
        wtot[t] = x;
    }
    __syncthreads();
    if (wv > 0) v += wtot[wv - 1];
    const int incl_c = (int)(v & 0xFFFFFu);
    const int incl_s = (int)(v >> 20);
    const int excl = incl_c - c;
    offsets[t] = excl;
    cursor[t]  = excl;
    const int segexcl = incl_s - nseg;
    for (int s = 0; s < nseg; ++s) items[segexcl + s] = (t << 12) | s;
    if (t == NPROTO - 1) *nitems = incl_s;
}

// ---------------- k3: scatter row indices into per-proto bins ----------------
__global__ __launch_bounds__(256) void scatter_kernel(
    const int* __restrict__ assign, int* __restrict__ cursor, int* __restrict__ bin)
{
    const int i = blockIdx.x * 256 + threadIdx.x;
    const int k = assign[i];
    const int pos = atomicAdd(&cursor[k], 1);
    bin[pos] = i;
}

// ---------------- k4A: per-segment partial sums -> psum (atomic fp32) ----------------
__global__ __launch_bounds__(256) void psum_kernel(
    const float* __restrict__ emb, const int* __restrict__ bin,
    const int* __restrict__ counts, const int* __restrict__ offsets,
    const float* __restrict__ invnorm, const int* __restrict__ items,
    const int* __restrict__ nitems, float* __restrict__ psum)
{
    if ((int)blockIdx.x >= *nitems) return;
    __shared__ float4 part[128];
    __shared__ int   sidx[256];
    __shared__ float sinv[256];
    const int item = items[blockIdx.x];
    const int k = item >> 12, seg = item & 4095;
    const int off = offsets[k], cnt = counts[k];
    const int s0 = seg * 256;
    const int n = min(256, cnt - s0);
    const int t = threadIdx.x;

    if (t < n) {
        const int r = bin[off + s0 + t];
        sidx[t] = r;
        sinv[t] = invnorm[r];
    }
    __syncthreads();

    const int par = t >> 7, colg = (t & 127) * 4;
    float4 acc = make_float4(0.f, 0.f, 0.f, 0.f);
    #pragma unroll 4
    for (int j = par; j < n; j += 2) {
        const int r = sidx[j];
        const float sc = sinv[j];
        const float4 v = *(const float4*)(emb + (size_t)r * D + colg);
        acc.x += v.x * sc; acc.y += v.y * sc; acc.z += v.z * sc; acc.w += v.w * sc;
    }

    if (par == 1) part[t & 127] = acc;
    __syncthreads();
    if (par == 0) {
        const float4 o = part[t];
        float* dst = psum + (size_t)k * D + colg;
        atomicAdd(dst + 0, acc.x + o.x);
        atomicAdd(dst + 1, acc.y + o.y);
        atomicAdd(dst + 2, acc.z + o.z);
        atomicAdd(dst + 3, acc.w + o.w);
    }
}

// ---------------- k4B: EMA + normalize ----------------
__global__ __launch_bounds__(128) void final_kernel(
    const float* __restrict__ protos, const float* __restrict__ psum,
    const int* __restrict__ counts, float* __restrict__ out)
{
    __shared__ float red[2];
    const int k = blockIdx.x, t = threadIdx.x;
    const int colg = t * 4;
    const int cnt = counts[k];
    const float denom = fmaxf((float)cnt, 1.0f);
    const float4 s  = *(const float4*)(psum + (size_t)k * D + colg);
    const float4 p4 = *(const float4*)(protos + (size_t)k * D + colg);
    float4 u;
    u.x = 0.9f * p4.x + 0.1f * s.x / denom;
    u.y = 0.9f * p4.y + 0.1f * s.y / denom;
    u.z = 0.9f * p4.z + 0.1f * s.z / denom;
    u.w = 0.9f * p4.w + 0.1f * s.w / denom;
    float ss = u.x*u.x + u.y*u.y + u.z*u.z + u.w*u.w;
    #pragma unroll
    for (int off = 32; off > 0; off >>= 1) ss += __shfl_xor(ss, off, 64);
    if ((t & 63) == 0) red[t >> 6] = ss;
    __syncthreads();
    const float tot = red[0] + red[1];
    const float inv = 1.0f / fmaxf(sqrtf(tot), 1e-6f);
    float4 o;
    o.x = (cnt > 0) ? u.x * inv : p4.x;
    o.y = (cnt > 0) ? u.y * inv : p4.y;
    o.z = (cnt > 0) ? u.z * inv : p4.z;
    o.w = (cnt > 0) ? u.w * inv : p4.w;
    *(float4*)(out + (size_t)k * D + colg) = o;
}

extern "C" void kernel_launch(void* const* d_in, const int* in_sizes, int n_in,
                              void* d_out, int out_size, void* d_ws, size_t ws_size,
                              hipStream_t stream)
{
    const float* emb    = (const float*)d_in[0];
    const float* protos = (const float*)d_in[1];
    float* out = (float*)d_out;
    const int n_emb = in_sizes[0] / D;        // 131072

    char* ws = (char*)d_ws;
    unsigned short* pbf = (unsigned short*)ws;                 // 1 MB packed bf16 protos
    int*   assign  = (int*)  (ws + (1 << 20));                 // 512 KB
    float* invnorm = (float*)(ws + (1 << 20) + (512 << 10));   // 512 KB
    int*   counts  = (int*)  (ws + (2 << 20));                 // 4 KB
    int*   offsets = (int*)  (ws + (2 << 20) + (4 << 10));     // 4 KB
    int*   cursor  = (int*)  (ws + (2 << 20) + (8 << 10));     // 4 KB
    int*   nitems  = (int*)  (ws + (2 << 20) + (12 << 10));    // 4 KB
    int*   items   = (int*)  (ws + (2 << 20) + (16 << 10));    // 8 KB (<=1536)
    int*   bin     = (int*)  (ws + (2 << 20) + (24 << 10));    // 512 KB
    float* psum    = (float*)(ws + (2 << 20) + (24 << 10) + (512 << 10)); // 2 MB

    norm_protos_kernel<<<NPROTO / 4, 256, 0, stream>>>(protos, pbf, counts, psum);
    assign_kernel<<<n_emb / ROWS, 512, 0, stream>>>(emb, pbf, assign, invnorm, counts);
    prefix_kernel<<<1, 1024, 0, stream>>>(counts, offsets, cursor, items, nitems);
    scatter_kernel<<<n_emb / 256, 256, 0, stream>>>(assign, cursor, bin);
    psum_kernel<<<1536, 256, 0, stream>>>(emb, bin, counts, offsets, invnorm,
                                          items, nitems, psum);
    final_kernel<<<NPROTO, 128, 0, stream>>>(protos, psum, counts, out);
}

// Round 8
// 563.866 us; speedup vs baseline: 1.0191x; 1.0191x over previous
//
#include <hip/hip_runtime.h>

// PrototypeBank steady-state update, MI355X/gfx950.  Round 12.
//   emb:    [131072, 512] fp32   protos: [1024, 512] fp32
//   out[k]: count>0 ? normalize(0.9*p + 0.1*mean(norm_emb assigned to k)) : p
//
// Round-12: R11's DMA ring worked but spilled (VGPR 128, WRITE 90MB) because
// ks(32) x ng(2) was FULLY unrolled -> 64 inline bodies of address CSE.
// Fix, not a new mechanism: DEPTH=4 ring, issue-ahead 3, vmcnt(6),
// #pragma unroll 4 (kk%4 static), no ng unroll, launch_bounds(512,2).
// LDS 132KB (eT 64 + ring 64 + merge 4) -> 1 block/CU, 8 waves, pipeline
// depth 3 covers the A-load latency with near-zero register cost.

#define D 512
#define NPROTO 1024
#define ROWS 64          // embedding rows per workgroup in k1
#define DEPTH 4          // A-ring slots per wave

typedef __attribute__((ext_vector_type(8)))  unsigned short ushort8;
typedef __attribute__((ext_vector_type(8)))  __bf16 bfrag8;
typedef __attribute__((ext_vector_type(16))) float f32x16;

static __device__ inline unsigned short f2bf(float f) {
    unsigned int u = __float_as_uint(f);
    u = u + 0x7FFFu + ((u >> 16) & 1u);   // round-to-nearest-even
    return (unsigned short)(u >> 16);
}

static __device__ __forceinline__ void gload16(const unsigned short* g,
                                               unsigned short* l) {
    __builtin_amdgcn_global_load_lds(
        (const __attribute__((address_space(1))) unsigned int*)g,
        (__attribute__((address_space(3))) unsigned int*)l, 16, 0, 0);
}

// ---------------- k0: normalize prototypes -> packed bf16 A-fragments ----------------
// Packed for 32x32x16 A-operand: group g32 = p>>5 (32 protos), k-step ks (16 cols).
// Consumer lane l reads ((g32*32+ks)*64 + l)*8 shorts.  Also zeroes psum + counts.
__global__ __launch_bounds__(256) void norm_protos_kernel(
    const float* __restrict__ protos, unsigned short* __restrict__ pbf,
    int* __restrict__ counts, float* __restrict__ psum)
{
    const int wave = threadIdx.x >> 6, lane = threadIdx.x & 63;
    const int row = blockIdx.x * 4 + wave;            // grid 256 -> 1024 rows
    const float* src = protos + (size_t)row * D + lane * 8;
    float4 v0 = *(const float4*)src;
    float4 v1 = *(const float4*)(src + 4);
    float ss = v0.x*v0.x + v0.y*v0.y + v0.z*v0.z + v0.w*v0.w
             + v1.x*v1.x + v1.y*v1.y + v1.z*v1.z + v1.w*v1.w;
    #pragma unroll
    for (int off = 32; off > 0; off >>= 1) ss += __shfl_xor(ss, off, 64);
    const float inv = 1.0f / fmaxf(sqrtf(ss), 1e-6f);
    ushort8 w;
    w[0] = f2bf(v0.x*inv); w[1] = f2bf(v0.y*inv); w[2] = f2bf(v0.z*inv); w[3] = f2bf(v0.w*inv);
    w[4] = f2bf(v1.x*inv); w[5] = f2bf(v1.y*inv); w[6] = f2bf(v1.z*inv); w[7] = f2bf(v1.w*inv);
    const size_t dst = (size_t)(row >> 5) * 16384 + (lane >> 1) * 512
                     + (lane & 1) * 256 + (row & 31) * 8;
    *(ushort8*)(pbf + dst) = w;
    const int gid = blockIdx.x * 256 + threadIdx.x;
    const float4 z = make_float4(0.f, 0.f, 0.f, 0.f);
    ((float4*)psum)[gid * 2]     = z;
    ((float4*)psum)[gid * 2 + 1] = z;
    if (blockIdx.x == 0) ((int4*)counts)[threadIdx.x] = (int4){0, 0, 0, 0};
}

// ---------------- k1: argmax over 1024 protos (32x32x16 bf16 MFMA) ----------------
// B: LDS eT 64x512 bf16, XOR-swizzled.  A: per-wave 4-slot LDS ring filled by
// global_load_lds DMA, issue-ahead 3, vmcnt(6) counted waits, no inner barriers.
__global__ __launch_bounds__(512, 2) void assign_kernel(
    const float* __restrict__ emb, const unsigned short* __restrict__ pbf,
    int* __restrict__ assign, float* __restrict__ invnorm, int* __restrict__ counts)
{
    __shared__ __align__(16) unsigned short eT[ROWS * D];            // 64 KB
    __shared__ __align__(16) unsigned short aring[8 * DEPTH * 1024]; // 64 KB
    __shared__ float swmax[8][64];                                   // 2 KB
    __shared__ int   swidx[8][64];                                   // 2 KB
    const int tid = threadIdx.x;
    const int wave = tid >> 6, lane = tid & 63;
    const int rowbase = blockIdx.x * ROWS;
    const int c32 = lane & 31, h = lane >> 5;

    // A-addresses: gA(kk,frag) = pbf + wave*2*16384 + lane*8
    //              + (kk>>5)*262144 + (kk&31)*512 + frag*16384   (shorts)
    const unsigned short* gA = pbf + (size_t)wave * 32768 + lane * 8;
    unsigned short* awu = aring + wave * (DEPTH * 1024);   // wave-uniform ring base

    // prologue: issue ring slots kk=0..2 (6 DMAs) BEFORE staging -> their
    // latency hides under the eT stage + barrier.  Wave-private, no barrier.
    #pragma unroll
    for (int kk = 0; kk < 3; ++kk) {
        const unsigned short* g0 = gA + kk * 512;          // kk<32 -> ng=0
        gload16(g0,         awu + kk * 1024);
        gload16(g0 + 16384, awu + kk * 1024 + 512);
    }

    // --- stage: 8 rows/wave, RAW bf16 (||e|| doesn't change argmax); invnorm saved.
    for (int rr = 0; rr < 8; ++rr) {
        const int rloc = wave * 8 + rr;
        const float* src = emb + (size_t)(rowbase + rloc) * D + lane * 8;
        float4 v0 = *(const float4*)src;
        float4 v1 = *(const float4*)(src + 4);
        float ss = v0.x*v0.x + v0.y*v0.y + v0.z*v0.z + v0.w*v0.w
                 + v1.x*v1.x + v1.y*v1.y + v1.z*v1.z + v1.w*v1.w;
        #pragma unroll
        for (int off = 32; off > 0; off >>= 1) ss += __shfl_xor(ss, off, 64);
        if (lane == 0) invnorm[rowbase + rloc] = 1.0f / fmaxf(sqrtf(ss), 1e-6f);
        ushort8 w;
        w[0] = f2bf(v0.x); w[1] = f2bf(v0.y); w[2] = f2bf(v0.z); w[3] = f2bf(v0.w);
        w[4] = f2bf(v1.x); w[5] = f2bf(v1.y); w[6] = f2bf(v1.z); w[7] = f2bf(v1.w);
        const int slot = lane ^ (rloc & 7);
        *(ushort8*)(&eT[rloc * D + slot * 8]) = w;
    }
    __syncthreads();

    float rv0 = -3.4e38f, rv1 = -3.4e38f;
    int   ri0 = 0,        ri1 = 0;

    const int bbase0 = c32 * D;            // shorts
    const int bbase1 = (32 + c32) * D;
    const int rxor = c32 & 7;

    for (int ng = 0; ng < 2; ++ng) {
        const int pbase = ng * 512 + wave * 64;

        f32x16 acc00 = (f32x16)(0.f), acc01 = (f32x16)(0.f);
        f32x16 acc10 = (f32x16)(0.f), acc11 = (f32x16)(0.f);

        // unroll 4 keeps kk%DEPTH static (DEPTH=4) without the 64-body
        // address-CSE register blowup that spilled R11.
        #pragma unroll 4
        for (int ks = 0; ks < 32; ++ks) {
            const int kk = ng * 32 + ks;
            // issue slot kk+3 (tail: clamp addr to kk=63, L2-hot dummy -> the
            // vmcnt literal stays uniform and in-order retirement covers it)
            {
                const int kkn = kk + 3;
                const int kkc = kkn > 63 ? 63 : kkn;
                const unsigned short* g0 = gA + (kkc >> 5) * 262144 + (kkc & 31) * 512;
                unsigned short* ld = awu + (kkn & (DEPTH - 1)) * 1024;
                gload16(g0,         ld);
                gload16(g0 + 16384, ld + 512);
            }
            // 3 younger slots x 2 loads may remain; slot kk's 2 must retire.
            asm volatile("s_waitcnt vmcnt(6)" ::: "memory");
            const unsigned short* ar = awu + (kk & (DEPTH - 1)) * 1024;
            const bfrag8 a0 = *(const bfrag8*)(ar + lane * 8);
            const bfrag8 a1 = *(const bfrag8*)(ar + 512 + lane * 8);
            const int slot = ((ks * 2 + h) ^ rxor) * 8;
            const bfrag8 b0 = *(const bfrag8*)(&eT[bbase0 + slot]);
            const bfrag8 b1 = *(const bfrag8*)(&eT[bbase1 + slot]);
            acc00 = __builtin_amdgcn_mfma_f32_32x32x16_bf16(a0, b0, acc00, 0, 0, 0);
            acc01 = __builtin_amdgcn_mfma_f32_32x32x16_bf16(a0, b1, acc01, 0, 0, 0);
            acc10 = __builtin_amdgcn_mfma_f32_32x32x16_bf16(a1, b0, acc10, 0, 0, 0);
            acc11 = __builtin_amdgcn_mfma_f32_32x32x16_bf16(a1, b1, acc11, 0, 0, 0);
        }

        // In-register argmax over protos.  C layout (32x32): col=lane&31,
        // row = (reg&3) + 8*(reg>>2) + 4*(lane>>5).  reg 0..15 then mt 0..1 is
        // strictly ascending proto index -> strict > keeps first max.
        float bv0 = -3.4e38f, bv1 = -3.4e38f;
        int   bi0 = 0,        bi1 = 0;
        #pragma unroll
        for (int j = 0; j < 16; ++j) {
            const int row = (j & 3) + 8 * (j >> 2) + 4 * h;
            const float v0 = acc00[j], v1 = acc01[j];
            if (v0 > bv0) { bv0 = v0; bi0 = pbase + row; }
            if (v1 > bv1) { bv1 = v1; bi1 = pbase + row; }
        }
        #pragma unroll
        for (int j = 0; j < 16; ++j) {
            const int row = 32 + (j & 3) + 8 * (j >> 2) + 4 * h;
            const float v0 = acc10[j], v1 = acc11[j];
            if (v0 > bv0) { bv0 = v0; bi0 = pbase + row; }
            if (v1 > bv1) { bv1 = v1; bi1 = pbase + row; }
        }
        // half-merge (other half owns interleaved rows; tie-break on index)
        {
            const float ov = __shfl_xor(bv0, 32, 64);
            const int   oi = __shfl_xor(bi0, 32, 64);
            if (ov > bv0 || (ov == bv0 && oi < bi0)) { bv0 = ov; bi0 = oi; }
        }
        {
            const float ov = __shfl_xor(bv1, 32, 64);
            const int   oi = __shfl_xor(bi1, 32, 64);
            if (ov > bv1 || (ov == bv1 && oi < bi1)) { bv1 = ov; bi1 = oi; }
        }
        // ng ascending: strictly-greater replaces; ties keep older (smaller idx)
        if (bv0 > rv0) { rv0 = bv0; ri0 = bi0; }
        if (bv1 > rv1) { rv1 = bv1; ri1 = bi1; }
    }

    // drain remaining dummy DMAs before LDS reuse / endpgm
    asm volatile("s_waitcnt vmcnt(0)" ::: "memory");

    if (h == 0) {
        swmax[wave][c32]      = rv0;  swidx[wave][c32]      = ri0;
        swmax[wave][32 + c32] = rv1;  swidx[wave][32 + c32] = ri1;
    }
    __syncthreads();

    if (tid < 64) {
        float v = swmax[0][tid]; int idx = swidx[0][tid];
        #pragma unroll
        for (int w = 1; w < 8; ++w) {
            const float ov = swmax[w][tid];
            const int   oi = swidx[w][tid];
            if (ov > v || (ov == v && oi < idx)) { v = ov; idx = oi; }
        }
        assign[rowbase + tid] = idx;
        atomicAdd(&counts[idx], 1);
    }
}

// ---------------- k2: packed shuffle-scan prefix + segment work-item list ----------------
__global__ __launch_bounds__(1024) void prefix_kernel(
    const int* __restrict__ counts, int* __restrict__ offsets,
    int* __restrict__ cursor, int* __restrict__ items, int* __restrict__ nitems)
{
    __shared__ unsigned wtot[16];
    const int t = threadIdx.x;
    const int lane = t & 63, wv = t >> 6;
    const int c = counts[t];
    const int nseg = (c + 255) >> 8;
    unsigned v = (unsigned)c | ((unsigned)nseg << 20);
    #pragma unroll
    for (int off = 1; off < 64; off <<= 1) {
        const unsigned n = __shfl_up(v, off, 64);
        if (lane >= off) v += n;
    }
    if (lane == 63) wtot[wv] = v;
    __syncthreads();
    if (t < 16) {
        unsigned x = wtot[t];
        #pragma unroll
        for (int off = 1; off < 16; off <<= 1) {
            const unsigned n = __shfl_up(x, off, 16);
            if (t >= off) x += n;
        }
        wtot[t] = x;
    }
    __syncthreads();
    if (wv > 0) v += wtot[wv - 1];
    const int incl_c = (int)(v & 0xFFFFFu);
    const int incl_s = (int)(v >> 20);
    const int excl = incl_c - c;
    offsets[t] = excl;
    cursor[t]  = excl;
    const int segexcl = incl_s - nseg;
    for (int s = 0; s < nseg; ++s) items[segexcl + s] = (t << 12) | s;
    if (t == NPROTO - 1) *nitems = incl_s;
}

// ---------------- k3: scatter row indices into per-proto bins ----------------
__global__ __launch_bounds__(256) void scatter_kernel(
    const int* __restrict__ assign, int* __restrict__ cursor, int* __restrict__ bin)
{
    const int i = blockIdx.x * 256 + threadIdx.x;
    const int k = assign[i];
    const int pos = atomicAdd(&cursor[k], 1);
    bin[pos] = i;
}

// ---------------- k4A: per-segment partial sums -> psum (atomic fp32) ----------------
__global__ __launch_bounds__(256) void psum_kernel(
    const float* __restrict__ emb, const int* __restrict__ bin,
    const int* __restrict__ counts, const int* __restrict__ offsets,
    const float* __restrict__ invnorm, const int* __restrict__ items,
    const int* __restrict__ nitems, float* __restrict__ psum)
{
    if ((int)blockIdx.x >= *nitems) return;
    __shared__ float4 part[128];
    __shared__ int   sidx[256];
    __shared__ float sinv[256];
    const int item = items[blockIdx.x];
    const int k = item >> 12, seg = item & 4095;
    const int off = offsets[k], cnt = counts[k];
    const int s0 = seg * 256;
    const int n = min(256, cnt - s0);
    const int t = threadIdx.x;

    if (t < n) {
        const int r = bin[off + s0 + t];
        sidx[t] = r;
        sinv[t] = invnorm[r];
    }
    __syncthreads();

    const int par = t >> 7, colg = (t & 127) * 4;
    float4 acc = make_float4(0.f, 0.f, 0.f, 0.f);
    #pragma unroll 4
    for (int j = par; j < n; j += 2) {
        const int r = sidx[j];
        const float sc = sinv[j];
        const float4 v = *(const float4*)(emb + (size_t)r * D + colg);
        acc.x += v.x * sc; acc.y += v.y * sc; acc.z += v.z * sc; acc.w += v.w * sc;
    }

    if (par == 1) part[t & 127] = acc;
    __syncthreads();
    if (par == 0) {
        const float4 o = part[t];
        float* dst = psum + (size_t)k * D + colg;
        atomicAdd(dst + 0, acc.x + o.x);
        atomicAdd(dst + 1, acc.y + o.y);
        atomicAdd(dst + 2, acc.z + o.z);
        atomicAdd(dst + 3, acc.w + o.w);
    }
}

// ---------------- k4B: EMA + normalize ----------------
__global__ __launch_bounds__(128) void final_kernel(
    const float* __restrict__ protos, const float* __restrict__ psum,
    const int* __restrict__ counts, float* __restrict__ out)
{
    __shared__ float red[2];
    const int k = blockIdx.x, t = threadIdx.x;
    const int colg = t * 4;
    const int cnt = counts[k];
    const float denom = fmaxf((float)cnt, 1.0f);
    const float4 s  = *(const float4*)(psum + (size_t)k * D + colg);
    const float4 p4 = *(const float4*)(protos + (size_t)k * D + colg);
    float4 u;
    u.x = 0.9f * p4.x + 0.1f * s.x / denom;
    u.y = 0.9f * p4.y + 0.1f * s.y / denom;
    u.z = 0.9f * p4.z + 0.1f * s.z / denom;
    u.w = 0.9f * p4.w + 0.1f * s.w / denom;
    float ss = u.x*u.x + u.y*u.y + u.z*u.z + u.w*u.w;
    #pragma unroll
    for (int off = 32; off > 0; off >>= 1) ss += __shfl_xor(ss, off, 64);
    if ((t & 63) == 0) red[t >> 6] = ss;
    __syncthreads();
    const float tot = red[0] + red[1];
    const float inv = 1.0f / fmaxf(sqrtf(tot), 1e-6f);
    float4 o;
    o.x = (cnt > 0) ? u.x * inv : p4.x;
    o.y = (cnt > 0) ? u.y * inv : p4.y;
    o.z = (cnt > 0) ? u.z * inv : p4.z;
    o.w = (cnt > 0) ? u.w * inv : p4.w;
    *(float4*)(out + (size_t)k * D + colg) = o;
}

extern "C" void kernel_launch(void* const* d_in, const int* in_sizes, int n_in,
                              void* d_out, int out_size, void* d_ws, size_t ws_size,
                              hipStream_t stream)
{
    const float* emb    = (const float*)d_in[0];
    const float* protos = (const float*)d_in[1];
    float* out = (float*)d_out;
    const int n_emb = in_sizes[0] / D;        // 131072

    char* ws = (char*)d_ws;
    unsigned short* pbf = (unsigned short*)ws;                 // 1 MB packed bf16 protos
    int*   assign  = (int*)  (ws + (1 << 20));                 // 512 KB
    float* invnorm = (float*)(ws + (1 << 20) + (512 << 10));   // 512 KB
    int*   counts  = (int*)  (ws + (2 << 20));                 // 4 KB
    int*   offsets = (int*)  (ws + (2 << 20) + (4 << 10));     // 4 KB
    int*   cursor  = (int*)  (ws + (2 << 20) + (8 << 10));     // 4 KB
    int*   nitems  = (int*)  (ws + (2 << 20) + (12 << 10));    // 4 KB
    int*   items   = (int*)  (ws + (2 << 20) + (16 << 10));    // 8 KB (<=1536)
    int*   bin     = (int*)  (ws + (2 << 20) + (24 << 10));    // 512 KB
    float* psum    = (float*)(ws + (2 << 20) + (24 << 10) + (512 << 10)); // 2 MB

    norm_protos_kernel<<<NPROTO / 4, 256, 0, stream>>>(protos, pbf, counts, psum);
    assign_kernel<<<n_emb / ROWS, 512, 0, stream>>>(emb, pbf, assign, invnorm, counts);
    prefix_kernel<<<1, 1024, 0, stream>>>(counts, offsets, cursor, items, nitems);
    scatter_kernel<<<n_emb / 256, 256, 0, stream>>>(assign, cursor, bin);
    psum_kernel<<<1536, 256, 0, stream>>>(emb, bin, counts, offsets, invnorm,
                                          items, nitems, psum);
    final_kernel<<<NPROTO, 128, 0, stream>>>(protos, psum, counts, out);
}